// Round 3
// baseline (15792.712 us; speedup 1.0000x reference)
//
#include <hip/hip_runtime.h>

// ---------------- problem constants ----------------
constexpr int N  = 325;   // nodes
constexpr int B  = 64;    // batch
constexpr int T  = 12;    // encoder steps
constexpr int HZ = 12;    // decoder horizon
constexpr int U  = 64;    // rnn units
constexpr int BN = B * N; // 20800 rows
constexpr int ELLW = 352; // ELL capacity >= N

constexpr int BLK   = 1024; // threads per block (16 waves), one block per batch
constexpr int TILES = 21;   // 336 = 21*16 MFMA row tiles
constexpr int LROWS = 336;  // LDS rows (padded for MFMA A-tiles)
constexpr int SST   = 36;   // f32 row stride (bank-friendly, 16B-aligned)
constexpr int ZST   = 36;   // u32 row stride for packed y2

typedef __attribute__((ext_vector_type(8))) short short8;
typedef __attribute__((ext_vector_type(4))) float floatx4;

// bf16 round-to-nearest-even + hi/lo split helpers
__device__ inline unsigned short f2bf(float f) {
    unsigned u = __float_as_uint(f);
    u += 0x7fff + ((u >> 16) & 1);
    return (unsigned short)(u >> 16);
}
__device__ inline unsigned pack_hilo(float v) {
    const unsigned short hi = f2bf(v);
    const float hif = __uint_as_float(((unsigned)hi) << 16);
    const unsigned short lo = f2bf(v - hif);
    return (unsigned)hi | ((unsigned)lo << 16);
}

// ---------------- setup kernels ----------------

// Build ELL (column-major, interleaved val/col) from dense S. One wave per row.
__global__ __launch_bounds__(64)
void ell_build(const float* __restrict__ S, float2* __restrict__ ellcv,
               int* __restrict__ nnz)
{
    const int m    = blockIdx.x;
    const int lane = threadIdx.x;
    const float* __restrict__ row = S + m * N;
    int count = 0;
    for (int base = 0; base < N; base += 64) {
        const int n = base + lane;
        const float v = (n < N) ? row[n] : 0.f;
        const unsigned long long mask = __ballot(v != 0.f);
        const int pre = __popcll(mask & ((1ull << lane) - 1ull));
        if (v != 0.f) {
            const int pos = count + pre;
            ellcv[pos * N + m] = make_float2(v, __int_as_float(n));
        }
        count += __popcll(mask);
    }
    if (lane == 0) nnz[m] = count;
}

// Pre-pack weights into MFMA B-fragment order with:
//  (a) chunk-major K permutation: packed p -> chunk c=p/96, level lvl=(p%96)/32,
//      feature f=p&31; original row k = lvl*F + (c*32+f)
//  (b) Chebyshev fold: W0' = W0 - W2, W1' = W1, W2' = 2*W2
//      (so the kernel computes y1 = S@x, y2 = S@y1 with NO subtract/scale)
__global__ __launch_bounds__(64)
void prepack_w(const float* __restrict__ W, short* __restrict__ Wh,
               short* __restrict__ Wl, int F, int Nout, int NT)
{
    const int kc = blockIdx.x, n = blockIdx.y, lane = threadIdx.x;
    const int quad = lane >> 4, l15 = lane & 15;
    short8 hv, lv;
    #pragma unroll
    for (int j = 0; j < 8; ++j) {
        const int p   = kc * 32 + quad * 8 + j;
        const int c   = p / 96;
        const int lvl = (p % 96) >> 5;
        const int f   = p & 31;
        const int cf  = c * 32 + f;
        const int col = n * 16 + l15;
        float w = 0.f;
        if (cf < F) {
            if (lvl == 0)
                w = W[(size_t)cf * Nout + col] - W[(size_t)(2 * F + cf) * Nout + col];
            else if (lvl == 1)
                w = W[(size_t)(F + cf) * Nout + col];
            else
                w = 2.f * W[(size_t)(2 * F + cf) * Nout + col];
        }
        const unsigned short hb = f2bf(w);
        hv[j] = (short)hb;
        lv[j] = (short)f2bf(w - __uint_as_float(((unsigned)hb) << 16));
    }
    const size_t off = ((size_t)(kc * NT + n) * 64 + lane);
    ((short8*)Wh)[off] = hv;
    ((short8*)Wl)[off] = lv;
}

// ---------------- per-batch fused kernel ----------------

struct MegaParams {
    const float2* ellcv;
    const int*    nnz;
    const float*  inputs;
    float* h0; float* h1; float* dec_in; float* ru;
    const short* Wgh[4]; const short* Wgl[4];
    const short* Wch[4]; const short* Wcl[4];
    const float* gb[4];  const float* cb[4];
    const float* pW; const float* pb;
    float* out;
};

// One full gconv+dense pass (gate OR candidate) for one batch, fully fused:
// per 32-feature chunk: stage -> y1=S@x (fp32) -> y2=S@y1 (packed) ->
// weight-MFMA partial accumulation (3 K-slices). Accumulators live in VGPRs
// across chunks. No global staging buffer.
template<int DIN, bool CAND, bool PROJ>
__device__ __forceinline__ void cell_pass(
    const float2* __restrict__ ellcv, const int* __restrict__ nnz,
    const float* __restrict__ x, float* __restrict__ h,
    float* __restrict__ ru, const short8* __restrict__ Wh,
    const short8* __restrict__ Wl, const float* __restrict__ bias,
    const float* __restrict__ pW, const float* __restrict__ pb,
    float* __restrict__ outp, float* __restrict__ dec_in,
    int b, float* __restrict__ s0, float* __restrict__ s1,
    unsigned* __restrict__ zc)
{
    constexpr int F   = DIN + U;
    constexpr int NCH = (F + 31) / 32;
    constexpr int NT  = CAND ? 4 : 8;
    const int tid  = threadIdx.x, wave = tid >> 6, lane = tid & 63;
    const int quad = lane >> 4, l15 = lane & 15;
    const int fg = (tid & 7) * 4;  // feature sub-offset {0,4,...,28}
    const int mi = tid >> 3;       // 0..127 rows in parallel

    floatx4 acc[2][NT];
    #pragma unroll
    for (int ti = 0; ti < 2; ++ti)
        #pragma unroll
        for (int n = 0; n < NT; ++n) {
            const float bv = bias[n * 16 + l15];
            acc[ti][n] = (floatx4){bv, bv, bv, bv};
        }

    for (int c = 0; c < NCH; ++c) {
        __syncthreads();   // protect s0/s1/zc from previous chunk's MFMA reads
        // ---- stage: s0 = concat(x, h or r*h) feature chunk (fp32) ----
        for (int idx = tid; idx < N * 32; idx += BLK) {
            const int n = idx >> 5, f = idx & 31, gf = c * 32 + f;
            float v = 0.f;
            if (gf < F) {
                const int row = b * N + n;
                if (gf < DIN) {
                    v = x[(size_t)row * DIN + gf];
                } else {
                    v = h[(size_t)row * U + (gf - DIN)];
                    if (CAND) v *= ru[(size_t)row * 128 + (gf - DIN)]; // r
                }
            }
            s0[n * SST + f] = v;
        }
        __syncthreads();
        // ---- y1 = S @ s0 -> s1 (fp32) ----
        for (int pass = 0; pass < 3; ++pass) {
            const int m = pass * 128 + mi;
            if (m < N) {
                const int cnt = nnz[m];
                float a0 = 0.f, a1 = 0.f, a2 = 0.f, a3 = 0.f;
                #pragma unroll 4
                for (int j = 0; j < cnt; ++j) {
                    const float2 cv = ellcv[j * N + m];
                    const int col = __float_as_int(cv.y);
                    const float4 v = *(const float4*)&s0[col * SST + fg];
                    a0 += cv.x * v.x; a1 += cv.x * v.y;
                    a2 += cv.x * v.z; a3 += cv.x * v.w;
                }
                *(float4*)&s1[m * SST + fg] = make_float4(a0, a1, a2, a3);
            }
        }
        __syncthreads();
        // ---- y2 = S @ s1 -> zc (packed bf16 hi/lo) ----
        for (int pass = 0; pass < 3; ++pass) {
            const int m = pass * 128 + mi;
            if (m < N) {
                const int cnt = nnz[m];
                float a0 = 0.f, a1 = 0.f, a2 = 0.f, a3 = 0.f;
                #pragma unroll 4
                for (int j = 0; j < cnt; ++j) {
                    const float2 cv = ellcv[j * N + m];
                    const int col = __float_as_int(cv.y);
                    const float4 v = *(const float4*)&s1[col * SST + fg];
                    a0 += cv.x * v.x; a1 += cv.x * v.y;
                    a2 += cv.x * v.z; a3 += cv.x * v.w;
                }
                uint4 pk;
                pk.x = pack_hilo(a0); pk.y = pack_hilo(a1);
                pk.z = pack_hilo(a2); pk.w = pack_hilo(a3);
                *(uint4*)&zc[m * ZST + fg] = pk;
            }
        }
        __syncthreads();
        // ---- weight MFMA: 3 K-slices {s0, s1, zc} x NT output tiles ----
        #pragma unroll
        for (int ti = 0; ti < 2; ++ti) {
            const int t = wave + ti * 16;
            if (t >= TILES) break;
            const int arow = t * 16 + l15;
            short8 ah[3], al[3];
            {   // slice 0: z0 from s0 (fp32 -> bf16 hi/lo on the fly)
                const float4 v0 = *(const float4*)&s0[arow * SST + quad * 8];
                const float4 v1 = *(const float4*)&s0[arow * SST + quad * 8 + 4];
                const float vv[8] = {v0.x, v0.y, v0.z, v0.w, v1.x, v1.y, v1.z, v1.w};
                #pragma unroll
                for (int j = 0; j < 8; ++j) {
                    const unsigned short hb = f2bf(vv[j]);
                    ah[0][j] = (short)hb;
                    al[0][j] = (short)f2bf(vv[j] - __uint_as_float(((unsigned)hb) << 16));
                }
            }
            {   // slice 1: y1 from s1
                const float4 v0 = *(const float4*)&s1[arow * SST + quad * 8];
                const float4 v1 = *(const float4*)&s1[arow * SST + quad * 8 + 4];
                const float vv[8] = {v0.x, v0.y, v0.z, v0.w, v1.x, v1.y, v1.z, v1.w};
                #pragma unroll
                for (int j = 0; j < 8; ++j) {
                    const unsigned short hb = f2bf(vv[j]);
                    ah[1][j] = (short)hb;
                    al[1][j] = (short)f2bf(vv[j] - __uint_as_float(((unsigned)hb) << 16));
                }
            }
            {   // slice 2: y2 from zc (already packed)
                const uint4 u0 = *(const uint4*)&zc[arow * ZST + quad * 8];
                const uint4 u1 = *(const uint4*)&zc[arow * ZST + quad * 8 + 4];
                const unsigned uu[8] = {u0.x, u0.y, u0.z, u0.w, u1.x, u1.y, u1.z, u1.w};
                #pragma unroll
                for (int j = 0; j < 8; ++j) {
                    ah[2][j] = (short)(uu[j] & 0xffffu);
                    al[2][j] = (short)(uu[j] >> 16);
                }
            }
            #pragma unroll
            for (int sl = 0; sl < 3; ++sl) {
                const short8* __restrict__ wh = Wh + (size_t)((c * 3 + sl) * NT) * 64 + lane;
                const short8* __restrict__ wl = Wl + (size_t)((c * 3 + sl) * NT) * 64 + lane;
                #pragma unroll
                for (int n = 0; n < NT; ++n) {
                    const short8 bh = wh[n * 64], bl = wl[n * 64];
                    acc[ti][n] = __builtin_amdgcn_mfma_f32_16x16x32_bf16(ah[sl], bh, acc[ti][n], 0, 0, 0);
                    acc[ti][n] = __builtin_amdgcn_mfma_f32_16x16x32_bf16(ah[sl], bl, acc[ti][n], 0, 0, 0);
                    acc[ti][n] = __builtin_amdgcn_mfma_f32_16x16x32_bf16(al[sl], bh, acc[ti][n], 0, 0, 0);
                }
            }
        }
    }

    // ---- epilogue ----
    if (!CAND) {
        #pragma unroll
        for (int ti = 0; ti < 2; ++ti) {
            const int t = wave + ti * 16;
            if (t >= TILES) break;
            #pragma unroll
            for (int n = 0; n < NT; ++n) {
                const int col = n * 16 + l15;
                #pragma unroll
                for (int r = 0; r < 4; ++r) {
                    const int row = t * 16 + quad * 4 + r;
                    if (row < N)
                        ru[(size_t)(b * N + row) * 128 + col] =
                            1.f / (1.f + __expf(-acc[ti][n][r]));
                }
            }
        }
    } else {
        #pragma unroll
        for (int ti = 0; ti < 2; ++ti) {
            const int t = wave + ti * 16;
            if (t >= TILES) break;
            float pr[4] = {0.f, 0.f, 0.f, 0.f};
            #pragma unroll
            for (int n = 0; n < NT; ++n) {
                const int col = n * 16 + l15;
                float pw = 0.f;
                if constexpr (PROJ) pw = pW[col];
                #pragma unroll
                for (int r = 0; r < 4; ++r) {
                    const int row = t * 16 + quad * 4 + r;
                    if (row < N) {
                        const size_t grow = (size_t)(b * N + row);
                        const float cc = tanhf(acc[ti][n][r]);
                        const float ug = ru[grow * 128 + 64 + col];  // u
                        const float hv = h[grow * 64 + col];
                        const float hn = ug * hv + (1.f - ug) * cc;
                        h[grow * 64 + col] = hn;
                        if constexpr (PROJ) pr[r] += hn * pw;
                    }
                }
            }
            if constexpr (PROJ) {
                #pragma unroll
                for (int r = 0; r < 4; ++r) {
                    float v = pr[r];
                    v += __shfl_xor(v, 1); v += __shfl_xor(v, 2);
                    v += __shfl_xor(v, 4); v += __shfl_xor(v, 8);
                    if (l15 == 0) {
                        const int row = t * 16 + quad * 4 + r;
                        if (row < N) {
                            const float o = v + pb[0];
                            outp[b * N + row]   = o;
                            dec_in[b * N + row] = o;
                        }
                    }
                }
            }
        }
    }
}

__global__ __launch_bounds__(BLK, 4)
void mega_kernel(MegaParams P)
{
    __shared__ __align__(16) float    s0[LROWS * SST];  // 48.4 KB
    __shared__ __align__(16) float    s1[LROWS * SST];  // 48.4 KB
    __shared__ __align__(16) unsigned zc[LROWS * ZST];  // 48.4 KB
    const int b = blockIdx.x;

    // zero LDS (padding rows must stay 0 forever) and this batch's state
    for (int i = threadIdx.x; i < LROWS * SST; i += BLK) {
        s0[i] = 0.f; s1[i] = 0.f; zc[i] = 0u;
    }
    for (int i = threadIdx.x; i < N * U; i += BLK) {
        P.h0[(size_t)b * N * U + i] = 0.f;
        P.h1[(size_t)b * N * U + i] = 0.f;
    }
    for (int i = threadIdx.x; i < N; i += BLK) P.dec_in[b * N + i] = 0.f;
    __syncthreads();

    // -------- encoder --------
    for (int t = 0; t < T; ++t) {
        const float* x = P.inputs + (size_t)t * BN * 2;
        cell_pass<2, false, false>(P.ellcv, P.nnz, x, P.h0, P.ru,
            (const short8*)P.Wgh[0], (const short8*)P.Wgl[0], P.gb[0],
            nullptr, nullptr, nullptr, nullptr, b, s0, s1, zc);
        cell_pass<2, true, false>(P.ellcv, P.nnz, x, P.h0, P.ru,
            (const short8*)P.Wch[0], (const short8*)P.Wcl[0], P.cb[0],
            nullptr, nullptr, nullptr, nullptr, b, s0, s1, zc);
        cell_pass<64, false, false>(P.ellcv, P.nnz, P.h0, P.h1, P.ru,
            (const short8*)P.Wgh[1], (const short8*)P.Wgl[1], P.gb[1],
            nullptr, nullptr, nullptr, nullptr, b, s0, s1, zc);
        cell_pass<64, true, false>(P.ellcv, P.nnz, P.h0, P.h1, P.ru,
            (const short8*)P.Wch[1], (const short8*)P.Wcl[1], P.cb[1],
            nullptr, nullptr, nullptr, nullptr, b, s0, s1, zc);
    }
    // -------- decoder --------
    for (int hz = 0; hz < HZ; ++hz) {
        cell_pass<1, false, false>(P.ellcv, P.nnz, P.dec_in, P.h0, P.ru,
            (const short8*)P.Wgh[2], (const short8*)P.Wgl[2], P.gb[2],
            nullptr, nullptr, nullptr, nullptr, b, s0, s1, zc);
        cell_pass<1, true, false>(P.ellcv, P.nnz, P.dec_in, P.h0, P.ru,
            (const short8*)P.Wch[2], (const short8*)P.Wcl[2], P.cb[2],
            nullptr, nullptr, nullptr, nullptr, b, s0, s1, zc);
        cell_pass<64, false, false>(P.ellcv, P.nnz, P.h0, P.h1, P.ru,
            (const short8*)P.Wgh[3], (const short8*)P.Wgl[3], P.gb[3],
            nullptr, nullptr, nullptr, nullptr, b, s0, s1, zc);
        cell_pass<64, true, true>(P.ellcv, P.nnz, P.h0, P.h1, P.ru,
            (const short8*)P.Wch[3], (const short8*)P.Wcl[3], P.cb[3],
            P.pW, P.pb, P.out + (size_t)hz * BN, P.dec_in, b, s0, s1, zc);
    }
}

// ---------------- host launcher ----------------

extern "C" void kernel_launch(void* const* d_in, const int* in_sizes, int n_in,
                              void* d_out, int out_size, void* d_ws, size_t ws_size,
                              hipStream_t stream)
{
    const float* inputs = (const float*)d_in[0];
    const float* S      = (const float*)d_in[1];
    const float* Wt[4][4];
    for (int l = 0; l < 4; ++l)
        for (int j = 0; j < 4; ++j)
            Wt[l][j] = (const float*)d_in[2 + l * 4 + j];
    const float* pW = (const float*)d_in[18];
    const float* pb = (const float*)d_in[19];
    float* out = (float*)d_out;

    // workspace layout (no global staging buffer anymore)
    float*    ws     = (float*)d_ws;
    float*    h0     = ws;                       // BN*U
    float*    h1     = h0 + BN * U;              // BN*U
    float*    dec_in = h1 + BN * U;              // BN
    float*    ru     = dec_in + BN;              // BN*128
    float2*   ellcv  = (float2*)(ru + (size_t)BN * 128);
    int*      nnz    = (int*)(ellcv + (size_t)ELLW * N);
    char*     wpbase = (char*)(nnz + ((N + 3) & ~3));
    wpbase = (char*)(((uintptr_t)wpbase + 15) & ~(uintptr_t)15);

    // layer geometry: F, chunk count, padded K (chunk-major: NCH*96)
    const int Fs[4]   = {66, 128, 65, 128};
    const int NCHs[4] = {3, 4, 3, 4};
    short *Wgh[4], *Wgl[4], *Wch[4], *Wcl[4];
    size_t off = 0;
    for (int l = 0; l < 4; ++l) {
        const size_t k3p = (size_t)NCHs[l] * 96;
        const size_t ge = k3p * 128, ce = k3p * 64;
        Wgh[l] = (short*)(wpbase + off); off += ge * 2;
        Wgl[l] = (short*)(wpbase + off); off += ge * 2;
        Wch[l] = (short*)(wpbase + off); off += ce * 2;
        Wcl[l] = (short*)(wpbase + off); off += ce * 2;
    }

    ell_build<<<N, 64, 0, stream>>>(S, ellcv, nnz);
    for (int l = 0; l < 4; ++l) {
        prepack_w<<<dim3(NCHs[l] * 3, 8), 64, 0, stream>>>(Wt[l][0], Wgh[l], Wgl[l],
                                                           Fs[l], 128, 8);
        prepack_w<<<dim3(NCHs[l] * 3, 4), 64, 0, stream>>>(Wt[l][2], Wch[l], Wcl[l],
                                                           Fs[l], 64, 4);
    }

    MegaParams P;
    P.ellcv = ellcv; P.nnz = nnz; P.inputs = inputs;
    P.h0 = h0; P.h1 = h1; P.dec_in = dec_in; P.ru = ru;
    for (int l = 0; l < 4; ++l) {
        P.Wgh[l] = Wgh[l]; P.Wgl[l] = Wgl[l];
        P.Wch[l] = Wch[l]; P.Wcl[l] = Wcl[l];
        P.gb[l] = Wt[l][1]; P.cb[l] = Wt[l][3];
    }
    P.pW = pW; P.pb = pb; P.out = out;

    mega_kernel<<<B, BLK, 0, stream>>>(P);
}

// Round 4
// 7621.350 us; speedup vs baseline: 2.0722x; 2.0722x over previous
//
#include <hip/hip_runtime.h>

// ---------------- problem constants ----------------
constexpr int N  = 325;   // nodes
constexpr int B  = 64;    // batch
constexpr int T  = 12;    // encoder steps
constexpr int HZ = 12;    // decoder horizon
constexpr int U  = 64;    // rnn units
constexpr int BN = B * N; // 20800 rows

// SS = [S ; S^2] stacked: rows [0,325)=S, [336,661)=S^2, M=672 (42 tiles)
constexpr int SSM   = 672;
constexpr int SSTIL = 42;   // row tiles
constexpr int SSKC  = 11;   // K chunks of 32 (K padded 325->352)

typedef __attribute__((ext_vector_type(8))) short short8;
typedef __attribute__((ext_vector_type(4))) float floatx4;

// bf16 round-to-nearest-even + hi/lo split helpers
__device__ inline unsigned short f2bf(float f) {
    unsigned u = __float_as_uint(f);
    u += 0x7fff + ((u >> 16) & 1);
    return (unsigned short)(u >> 16);
}
__device__ inline unsigned pack_hilo(float v) {
    const unsigned short hi = f2bf(v);
    const float hif = __uint_as_float(((unsigned)hi) << 16);
    const unsigned short lo = f2bf(v - hif);
    return (unsigned)hi | ((unsigned)lo << 16);
}

// ---------------- setup kernels ----------------

__global__ void zero_kernel(unsigned* __restrict__ p, long n) {
    long i = (long)blockIdx.x * blockDim.x + threadIdx.x;
    const long stride = (long)gridDim.x * blockDim.x;
    for (; i < n; i += stride) p[i] = 0u;
}

// S2 = S @ S (fp32, exact-ish). One block per output row.
__global__ __launch_bounds__(256)
void s2_build(const float* __restrict__ S, float* __restrict__ S2)
{
    const int m = blockIdx.x;
    __shared__ float srow[N];
    for (int i = threadIdx.x; i < N; i += 256) srow[i] = S[m * N + i];
    __syncthreads();
    for (int c = threadIdx.x; c < N; c += 256) {
        float a = 0.f;
        for (int k = 0; k < N; ++k) a += srow[k] * S[k * N + c];
        S2[m * N + c] = a;
    }
}

// Prepack SS=[S;S2] into MFMA A-fragments (bf16 hi/lo).
// A-frag: lane l holds A[row = t*16 + (l&15)][k = kc*32 + (l>>4)*8 + j].
__global__ __launch_bounds__(64)
void prepack_ss(const float* __restrict__ S, const float* __restrict__ S2,
                short* __restrict__ ssh, short* __restrict__ ssl)
{
    const int t = blockIdx.x, kc = blockIdx.y, lane = threadIdx.x;
    const int quad = lane >> 4, l15 = lane & 15;
    short8 hv, lv;
    #pragma unroll
    for (int j = 0; j < 8; ++j) {
        const int m = t * 16 + l15;
        const int k = kc * 32 + quad * 8 + j;
        float v = 0.f;
        if (k < N) {
            if (m < N) v = S[m * N + k];
            else if (m >= 336 && m < 336 + N) v = S2[(m - 336) * N + k];
        }
        const unsigned short hb = f2bf(v);
        hv[j] = (short)hb;
        lv[j] = (short)f2bf(v - __uint_as_float(((unsigned)hb) << 16));
    }
    const size_t off = ((size_t)(t * SSKC + kc) * 64 + lane);
    ((short8*)ssh)[off] = hv;
    ((short8*)ssl)[off] = lv;
}

// Prepack weights (3F x Nout fp32, level-major) into MFMA B-fragment order,
// bf16 hi/lo, K padded to K3P, with Chebyshev fold:
//   W0' = W0 - W2, W1' = W1, W2' = 2*W2
// so the cell computes y1 = S@x, y2 = S^2@x (no subtract/scale downstream).
// B-frag: lane l holds B[k = kc*32+(l>>4)*8+j][col = n*16+(l&15)].
__global__ __launch_bounds__(64)
void prepack_w(const float* __restrict__ W, short* __restrict__ Wh,
               short* __restrict__ Wl, int F, int Nout, int NT)
{
    const int kc = blockIdx.x, n = blockIdx.y, lane = threadIdx.x;
    const int quad = lane >> 4, l15 = lane & 15;
    short8 hv, lv;
    #pragma unroll
    for (int j = 0; j < 8; ++j) {
        const int k   = kc * 32 + quad * 8 + j;
        const int col = n * 16 + l15;
        const int lvl = k / F, f = k - lvl * F;
        float w = 0.f;
        if (lvl == 0)
            w = W[(size_t)f * Nout + col] - W[(size_t)(2 * F + f) * Nout + col];
        else if (lvl == 1)
            w = W[(size_t)(F + f) * Nout + col];
        else if (lvl == 2)
            w = 2.f * W[(size_t)(2 * F + f) * Nout + col];
        const unsigned short hb = f2bf(w);
        hv[j] = (short)hb;
        lv[j] = (short)f2bf(w - __uint_as_float(((unsigned)hb) << 16));
    }
    const size_t off = ((size_t)(kc * NT + n) * 64 + lane);
    ((short8*)Wh)[off] = hv;
    ((short8*)Wl)[off] = lv;
}

// ---------------- diffusion GEMM ----------------
// Y = SS @ X_b for one (batch, 32-col feature chunk). X built on the fly from
// (x, h [, r]); writes packed z = [z0 | y1 | y2] sections of zcat.
// 448 threads = 7 waves; wave w owns row tiles [6w, 6w+6).
template<int DIN, int F, int K3P, bool RMUL>
__global__ __launch_bounds__(448)
void diffuse_mfma(const short8* __restrict__ ssh, const short8* __restrict__ ssl,
                  const float* __restrict__ x, const float* __restrict__ h,
                  const float* __restrict__ ru, unsigned* __restrict__ zcat)
{
    const int cx = blockIdx.x, b = blockIdx.y;
    const int c0 = cx * 32;
    const int tid = threadIdx.x, wave = tid >> 6, lane = tid & 63;
    const int quad = lane >> 4, l15 = lane & 15;

    __shared__ unsigned xls[352 * 33];  // [k][col], stride 33 u32 (46.5 KB)

    // stage X chunk (packed bf16 hi/lo) + write z0 section
    for (int idx = tid; idx < 352 * 32; idx += 448) {
        const int n = idx >> 5, f = idx & 31, gf = c0 + f;
        unsigned u = 0u;
        if (n < N && gf < F) {
            const int row = b * N + n;
            float v;
            if (gf < DIN) {
                v = x[(size_t)row * DIN + gf];
            } else {
                v = h[(size_t)row * U + (gf - DIN)];
                if (RMUL) v *= ru[(size_t)row * 128 + (gf - DIN)];  // r = ru[:,:64]
            }
            u = pack_hilo(v);
            if (!(RMUL && gf < DIN))   // x-part identical to gate pass
                zcat[(size_t)row * K3P + gf] = u;
        }
        xls[n * 33 + f] = u;
    }
    __syncthreads();

    floatx4 acc[6][2];
    #pragma unroll
    for (int i = 0; i < 6; ++i)
        #pragma unroll
        for (int n = 0; n < 2; ++n)
            acc[i][n] = (floatx4){0.f, 0.f, 0.f, 0.f};

    for (int kc = 0; kc < SSKC; ++kc) {
        short8 bh[2], bl[2];
        #pragma unroll
        for (int n = 0; n < 2; ++n)
            #pragma unroll
            for (int j = 0; j < 8; ++j) {
                const unsigned u = xls[(kc * 32 + quad * 8 + j) * 33 + n * 16 + l15];
                bh[n][j] = (short)(u & 0xffffu);
                bl[n][j] = (short)(u >> 16);
            }
        #pragma unroll
        for (int i = 0; i < 6; ++i) {
            const int t = wave * 6 + i;
            const size_t fo = (size_t)(t * SSKC + kc) * 64 + lane;
            const short8 ah = ssh[fo], al = ssl[fo];
            #pragma unroll
            for (int n = 0; n < 2; ++n) {
                acc[i][n] = __builtin_amdgcn_mfma_f32_16x16x32_bf16(ah, bh[n], acc[i][n], 0, 0, 0);
                acc[i][n] = __builtin_amdgcn_mfma_f32_16x16x32_bf16(ah, bl[n], acc[i][n], 0, 0, 0);
                acc[i][n] = __builtin_amdgcn_mfma_f32_16x16x32_bf16(al, bh[n], acc[i][n], 0, 0, 0);
            }
        }
    }

    // epilogue: C/D row=(lane>>4)*4+r, col=lane&15. Rows <325 -> y1 (sect F);
    // rows 336..660 -> y2 (sect 2F); pad rows dropped.
    #pragma unroll
    for (int i = 0; i < 6; ++i) {
        const int t = wave * 6 + i;
        #pragma unroll
        for (int n = 0; n < 2; ++n) {
            const int col = c0 + n * 16 + l15;
            if (col >= F) continue;
            #pragma unroll
            for (int r = 0; r < 4; ++r) {
                const int m = t * 16 + quad * 4 + r;
                if (m < N)
                    zcat[(size_t)(b * N + m) * K3P + F + col] = pack_hilo(acc[i][n][r]);
                else if (m >= 336 && m < 336 + N)
                    zcat[(size_t)(b * N + (m - 336)) * K3P + 2 * F + col] = pack_hilo(acc[i][n][r]);
            }
        }
    }
}

// ---------------- dense gate / candidate (round-0 proven) ----------------

__global__ __launch_bounds__(256)
void dense_gate_mfma(const unsigned* __restrict__ zcat, int K3p,
                     const short8* __restrict__ Wh, const short8* __restrict__ Wl,
                     const float* __restrict__ bias, float* __restrict__ ru)
{
    constexpr int NT = 8;
    const int tid = threadIdx.x, wave = tid >> 6, lane = tid & 63;
    const int quad = lane >> 4, l15 = lane & 15;
    const int row0 = blockIdx.x * 64 + wave * 16;

    floatx4 acc[NT];
    #pragma unroll
    for (int n = 0; n < NT; ++n) {
        const float bv = bias[n * 16 + l15];
        acc[n] = (floatx4){bv, bv, bv, bv};
    }
    const unsigned* __restrict__ zrow = zcat + (size_t)(row0 + l15) * K3p + quad * 8;
    const int KC = K3p >> 5;
    for (int kc = 0; kc < KC; ++kc) {
        const uint4* p = (const uint4*)(zrow + kc * 32);
        const uint4 u0 = p[0], u1 = p[1];
        const unsigned uu[8] = {u0.x, u0.y, u0.z, u0.w, u1.x, u1.y, u1.z, u1.w};
        short8 ahi, alo;
        #pragma unroll
        for (int j = 0; j < 8; ++j) {
            ahi[j] = (short)(uu[j] & 0xffffu);
            alo[j] = (short)(uu[j] >> 16);
        }
        const short8* __restrict__ wh = Wh + (size_t)(kc * NT) * 64 + lane;
        const short8* __restrict__ wl = Wl + (size_t)(kc * NT) * 64 + lane;
        #pragma unroll
        for (int n = 0; n < NT; ++n) {
            const short8 bh = wh[n * 64], bl = wl[n * 64];
            acc[n] = __builtin_amdgcn_mfma_f32_16x16x32_bf16(ahi, bh, acc[n], 0, 0, 0);
            acc[n] = __builtin_amdgcn_mfma_f32_16x16x32_bf16(ahi, bl, acc[n], 0, 0, 0);
            acc[n] = __builtin_amdgcn_mfma_f32_16x16x32_bf16(alo, bh, acc[n], 0, 0, 0);
        }
    }
    #pragma unroll
    for (int n = 0; n < NT; ++n) {
        const int col = n * 16 + l15;
        #pragma unroll
        for (int r = 0; r < 4; ++r) {
            const int row = row0 + quad * 4 + r;
            ru[(size_t)row * 128 + col] = 1.f / (1.f + __expf(-acc[n][r]));
        }
    }
}

template<bool PROJ>
__global__ __launch_bounds__(256)
void dense_cand_mfma(const unsigned* __restrict__ zcat, int K3p,
                     const short8* __restrict__ Wh, const short8* __restrict__ Wl,
                     const float* __restrict__ bias, const float* __restrict__ ru,
                     float* __restrict__ h, const float* __restrict__ pW,
                     const float* __restrict__ pb, float* __restrict__ outp,
                     float* __restrict__ dec_in)
{
    constexpr int NT = 4;
    const int tid = threadIdx.x, wave = tid >> 6, lane = tid & 63;
    const int quad = lane >> 4, l15 = lane & 15;
    const int row0 = blockIdx.x * 64 + wave * 16;

    floatx4 acc[NT];
    #pragma unroll
    for (int n = 0; n < NT; ++n) {
        const float bv = bias[n * 16 + l15];
        acc[n] = (floatx4){bv, bv, bv, bv};
    }
    const unsigned* __restrict__ zrow = zcat + (size_t)(row0 + l15) * K3p + quad * 8;
    const int KC = K3p >> 5;
    for (int kc = 0; kc < KC; ++kc) {
        const uint4* p = (const uint4*)(zrow + kc * 32);
        const uint4 u0 = p[0], u1 = p[1];
        const unsigned uu[8] = {u0.x, u0.y, u0.z, u0.w, u1.x, u1.y, u1.z, u1.w};
        short8 ahi, alo;
        #pragma unroll
        for (int j = 0; j < 8; ++j) {
            ahi[j] = (short)(uu[j] & 0xffffu);
            alo[j] = (short)(uu[j] >> 16);
        }
        const short8* __restrict__ wh = Wh + (size_t)(kc * NT) * 64 + lane;
        const short8* __restrict__ wl = Wl + (size_t)(kc * NT) * 64 + lane;
        #pragma unroll
        for (int n = 0; n < NT; ++n) {
            const short8 bh = wh[n * 64], bl = wl[n * 64];
            acc[n] = __builtin_amdgcn_mfma_f32_16x16x32_bf16(ahi, bh, acc[n], 0, 0, 0);
            acc[n] = __builtin_amdgcn_mfma_f32_16x16x32_bf16(ahi, bl, acc[n], 0, 0, 0);
            acc[n] = __builtin_amdgcn_mfma_f32_16x16x32_bf16(alo, bh, acc[n], 0, 0, 0);
        }
    }
    float pr[4] = {0.f, 0.f, 0.f, 0.f};
    #pragma unroll
    for (int n = 0; n < NT; ++n) {
        const int col = n * 16 + l15;
        float pw = 0.f;
        if constexpr (PROJ) pw = pW[col];
        #pragma unroll
        for (int r = 0; r < 4; ++r) {
            const int row = row0 + quad * 4 + r;
            const float c  = tanhf(acc[n][r]);
            const float ug = ru[(size_t)row * 128 + 64 + col];  // u = ru[:,64:]
            const float hv = h[(size_t)row * 64 + col];
            const float hn = ug * hv + (1.f - ug) * c;
            h[(size_t)row * 64 + col] = hn;
            if constexpr (PROJ) pr[r] += hn * pw;
        }
    }
    if constexpr (PROJ) {
        #pragma unroll
        for (int r = 0; r < 4; ++r) {
            float v = pr[r];
            v += __shfl_xor(v, 1); v += __shfl_xor(v, 2);
            v += __shfl_xor(v, 4); v += __shfl_xor(v, 8);
            if (l15 == 0) {
                const int row = row0 + quad * 4 + r;
                const float o = v + pb[0];
                outp[row]   = o;
                dec_in[row] = o;
            }
        }
    }
}

// ---------------- host launcher ----------------

extern "C" void kernel_launch(void* const* d_in, const int* in_sizes, int n_in,
                              void* d_out, int out_size, void* d_ws, size_t ws_size,
                              hipStream_t stream)
{
    const float* inputs = (const float*)d_in[0];
    const float* S      = (const float*)d_in[1];
    const float* Wt[4][4];
    for (int l = 0; l < 4; ++l)
        for (int j = 0; j < 4; ++j)
            Wt[l][j] = (const float*)d_in[2 + l * 4 + j];
    const float* pW = (const float*)d_in[18];
    const float* pb = (const float*)d_in[19];
    float* out = (float*)d_out;

    // workspace layout
    float*    ws     = (float*)d_ws;
    float*    h0     = ws;                        // BN*64
    float*    h1     = h0 + (size_t)BN * U;       // BN*64
    float*    dec_in = h1 + (size_t)BN * U;       // BN
    float*    ru     = dec_in + BN;               // BN*128
    unsigned* zcat   = (unsigned*)(ru + (size_t)BN * 128);  // BN*384 (shared 224/384)
    float*    S2     = (float*)(zcat + (size_t)BN * 384);   // N*N
    char*     pp     = (char*)(S2 + (size_t)N * N);
    pp = (char*)(((uintptr_t)pp + 15) & ~(uintptr_t)15);

    short* ssh = (short*)pp;                      // 42*11*64*8 shorts
    short* ssl = ssh + (size_t)SSTIL * SSKC * 64 * 8;
    char*  wpbase = (char*)(ssl + (size_t)SSTIL * SSKC * 64 * 8);

    const int Fs[4]   = {66, 128, 65, 128};
    const int K3ps[4] = {224, 384, 224, 384};
    short *Wgh[4], *Wgl[4], *Wch[4], *Wcl[4];
    size_t off = 0;
    for (int l = 0; l < 4; ++l) {
        const size_t ge = (size_t)K3ps[l] * 128, ce = (size_t)K3ps[l] * 64;
        Wgh[l] = (short*)(wpbase + off); off += ge * 2;
        Wgl[l] = (short*)(wpbase + off); off += ge * 2;
        Wch[l] = (short*)(wpbase + off); off += ce * 2;
        Wcl[l] = (short*)(wpbase + off); off += ce * 2;
    }

    // zero state + zcat (avoid NaN bit patterns in pad strips on first use)
    const long zn = (long)BN * (U + U + 128) + BN + (long)BN * 384;
    zero_kernel<<<2048, 256, 0, stream>>>((unsigned*)h0, zn);

    s2_build<<<N, 256, 0, stream>>>(S, S2);
    prepack_ss<<<dim3(SSTIL, SSKC), 64, 0, stream>>>(S, S2, ssh, ssl);
    for (int l = 0; l < 4; ++l) {
        prepack_w<<<dim3(K3ps[l] / 32, 8), 64, 0, stream>>>(Wt[l][0], Wgh[l], Wgl[l],
                                                            Fs[l], 128, 8);
        prepack_w<<<dim3(K3ps[l] / 32, 4), 64, 0, stream>>>(Wt[l][2], Wch[l], Wcl[l],
                                                            Fs[l], 64, 4);
    }

    const short8* SSH = (const short8*)ssh;
    const short8* SSL = (const short8*)ssl;

    // -------- encoder --------
    for (int t = 0; t < T; ++t) {
        const float* x = inputs + (size_t)t * BN * 2;
        // layer 0: DIN=2, F=66, K3P=224, 3 chunks
        diffuse_mfma<2, 66, 224, false><<<dim3(3, B), 448, 0, stream>>>(SSH, SSL, x, h0, ru, zcat);
        dense_gate_mfma<<<BN / 64, 256, 0, stream>>>(zcat, 224, (short8*)Wgh[0], (short8*)Wgl[0], Wt[0][1], ru);
        diffuse_mfma<2, 66, 224, true><<<dim3(3, B), 448, 0, stream>>>(SSH, SSL, x, h0, ru, zcat);
        dense_cand_mfma<false><<<BN / 64, 256, 0, stream>>>(zcat, 224, (short8*)Wch[0], (short8*)Wcl[0],
                                                            Wt[0][3], ru, h0, nullptr, nullptr, nullptr, nullptr);
        // layer 1: DIN=64, F=128, K3P=384, 4 chunks
        diffuse_mfma<64, 128, 384, false><<<dim3(4, B), 448, 0, stream>>>(SSH, SSL, h0, h1, ru, zcat);
        dense_gate_mfma<<<BN / 64, 256, 0, stream>>>(zcat, 384, (short8*)Wgh[1], (short8*)Wgl[1], Wt[1][1], ru);
        diffuse_mfma<64, 128, 384, true><<<dim3(4, B), 448, 0, stream>>>(SSH, SSL, h0, h1, ru, zcat);
        dense_cand_mfma<false><<<BN / 64, 256, 0, stream>>>(zcat, 384, (short8*)Wch[1], (short8*)Wcl[1],
                                                            Wt[1][3], ru, h1, nullptr, nullptr, nullptr, nullptr);
    }
    // -------- decoder --------
    for (int hz = 0; hz < HZ; ++hz) {
        // layer 0: DIN=1, F=65, K3P=224, 3 chunks
        diffuse_mfma<1, 65, 224, false><<<dim3(3, B), 448, 0, stream>>>(SSH, SSL, dec_in, h0, ru, zcat);
        dense_gate_mfma<<<BN / 64, 256, 0, stream>>>(zcat, 224, (short8*)Wgh[2], (short8*)Wgl[2], Wt[2][1], ru);
        diffuse_mfma<1, 65, 224, true><<<dim3(3, B), 448, 0, stream>>>(SSH, SSL, dec_in, h0, ru, zcat);
        dense_cand_mfma<false><<<BN / 64, 256, 0, stream>>>(zcat, 224, (short8*)Wch[2], (short8*)Wcl[2],
                                                            Wt[2][3], ru, h0, nullptr, nullptr, nullptr, nullptr);
        // layer 1 + fused projection
        diffuse_mfma<64, 128, 384, false><<<dim3(4, B), 448, 0, stream>>>(SSH, SSL, h0, h1, ru, zcat);
        dense_gate_mfma<<<BN / 64, 256, 0, stream>>>(zcat, 384, (short8*)Wgh[3], (short8*)Wgl[3], Wt[3][1], ru);
        diffuse_mfma<64, 128, 384, true><<<dim3(4, B), 448, 0, stream>>>(SSH, SSL, h0, h1, ru, zcat);
        dense_cand_mfma<true><<<BN / 64, 256, 0, stream>>>(zcat, 384, (short8*)Wch[3], (short8*)Wcl[3],
                                                           Wt[3][3], ru, h1, pW, pb,
                                                           out + (size_t)hz * BN, dec_in);
    }
}

// Round 5
// 4517.712 us; speedup vs baseline: 3.4957x; 1.6870x over previous
//
#include <hip/hip_runtime.h>

// ---------------- problem constants ----------------
constexpr int N  = 325;   // nodes
constexpr int B  = 64;    // batch
constexpr int T  = 12;    // encoder steps
constexpr int HZ = 12;    // decoder horizon
constexpr int U  = 64;    // rnn units
constexpr int BN = B * N; // 20800 rows

// SS = [S ; S^2] stacked: rows [0,325)=S, [336,661)=S^2, M=672 (42 tiles)
constexpr int SSM   = 672;
constexpr int SSTIL = 42;   // row tiles
constexpr int SSKC  = 11;   // K chunks of 32 (K padded 325->352)

typedef __attribute__((ext_vector_type(8))) short short8;
typedef __attribute__((ext_vector_type(4))) float floatx4;

// bf16 round-to-nearest-even + hi/lo split helpers
__device__ inline unsigned short f2bf(float f) {
    unsigned u = __float_as_uint(f);
    u += 0x7fff + ((u >> 16) & 1);
    return (unsigned short)(u >> 16);
}
__device__ inline unsigned pack_hilo(float v) {
    const unsigned short hi = f2bf(v);
    const float hif = __uint_as_float(((unsigned)hi) << 16);
    const unsigned short lo = f2bf(v - hif);
    return (unsigned)hi | ((unsigned)lo << 16);
}

// ---------------- setup kernels ----------------

__global__ void zero_kernel(unsigned* __restrict__ p, long n) {
    long i = (long)blockIdx.x * blockDim.x + threadIdx.x;
    const long stride = (long)gridDim.x * blockDim.x;
    for (; i < n; i += stride) p[i] = 0u;
}

// S2 = S @ S (fp32). One block per output row.
__global__ __launch_bounds__(256)
void s2_build(const float* __restrict__ S, float* __restrict__ S2)
{
    const int m = blockIdx.x;
    __shared__ float srow[N];
    for (int i = threadIdx.x; i < N; i += 256) srow[i] = S[m * N + i];
    __syncthreads();
    for (int c = threadIdx.x; c < N; c += 256) {
        float a = 0.f;
        for (int k = 0; k < N; ++k) a += srow[k] * S[k * N + c];
        S2[m * N + c] = a;
    }
}

// Prepack SS=[S;S2] into MFMA A-fragments (bf16 hi/lo).
// A-frag: lane l holds A[row = t*16 + (l&15)][k = kc*32 + (l>>4)*8 + j].
__global__ __launch_bounds__(64)
void prepack_ss(const float* __restrict__ S, const float* __restrict__ S2,
                short* __restrict__ ssh, short* __restrict__ ssl)
{
    const int t = blockIdx.x, kc = blockIdx.y, lane = threadIdx.x;
    const int quad = lane >> 4, l15 = lane & 15;
    short8 hv, lv;
    #pragma unroll
    for (int j = 0; j < 8; ++j) {
        const int m = t * 16 + l15;
        const int k = kc * 32 + quad * 8 + j;
        float v = 0.f;
        if (k < N) {
            if (m < N) v = S[m * N + k];
            else if (m >= 336 && m < 336 + N) v = S2[(m - 336) * N + k];
        }
        const unsigned short hb = f2bf(v);
        hv[j] = (short)hb;
        lv[j] = (short)f2bf(v - __uint_as_float(((unsigned)hb) << 16));
    }
    const size_t off = ((size_t)(t * SSKC + kc) * 64 + lane);
    ((short8*)ssh)[off] = hv;
    ((short8*)ssl)[off] = lv;
}

// Prepack weights (3F x Nout fp32, level-major) into MFMA B-fragment order,
// bf16 hi/lo, K padded to K3P, with Chebyshev fold:
//   W0' = W0 - W2, W1' = W1, W2' = 2*W2
// so the cell computes y1 = S@x, y2 = S^2@x (no subtract/scale downstream).
// B-frag: lane l holds B[k = kc*32+(l>>4)*8+j][col = n*16+(l&15)].
__global__ __launch_bounds__(64)
void prepack_w(const float* __restrict__ W, short* __restrict__ Wh,
               short* __restrict__ Wl, int F, int Nout, int NT)
{
    const int kc = blockIdx.x, n = blockIdx.y, lane = threadIdx.x;
    const int quad = lane >> 4, l15 = lane & 15;
    short8 hv, lv;
    #pragma unroll
    for (int j = 0; j < 8; ++j) {
        const int k   = kc * 32 + quad * 8 + j;
        const int col = n * 16 + l15;
        const int lvl = k / F, f = k - lvl * F;
        float w = 0.f;
        if (lvl == 0)
            w = W[(size_t)f * Nout + col] - W[(size_t)(2 * F + f) * Nout + col];
        else if (lvl == 1)
            w = W[(size_t)(F + f) * Nout + col];
        else if (lvl == 2)
            w = 2.f * W[(size_t)(2 * F + f) * Nout + col];
        const unsigned short hb = f2bf(w);
        hv[j] = (short)hb;
        lv[j] = (short)f2bf(w - __uint_as_float(((unsigned)hb) << 16));
    }
    const size_t off = ((size_t)(kc * NT + n) * 64 + lane);
    ((short8*)Wh)[off] = hv;
    ((short8*)Wl)[off] = lv;
}

// ---------------- diffusion GEMM ----------------
// Y = SS @ X_b for one (batch, 32-col feature chunk, M-half). X built on the
// fly from (x, h [, r]); writes packed z = [z0 | y1 | y2] sections of zcat.
// 448 threads = 7 waves; wave w owns 3 row tiles; blockIdx.z picks M half.
template<int DIN, int F, int K3P, bool RMUL>
__global__ __launch_bounds__(448, 3)
void diffuse_mfma(const short8* __restrict__ ssh, const short8* __restrict__ ssl,
                  const float* __restrict__ x, const float* __restrict__ h,
                  const float* __restrict__ ru, unsigned* __restrict__ zcat)
{
    constexpr int XST = 364;  // u32 stride per column (uint4-aligned; 2-way banks)
    const int cx = blockIdx.x, b = blockIdx.y, mh = blockIdx.z;
    const int c0 = cx * 32;
    const int tid = threadIdx.x, wave = tid >> 6, lane = tid & 63;
    const int quad = lane >> 4, l15 = lane & 15;

    __shared__ unsigned xls[32 * XST];  // [col][k] packed bf16 hi/lo, 46.6 KB

    // stage X chunk: global side coalesced (f fastest); LDS col-major write.
    // z0 section written by half-0 blocks only (identical data).
    for (int idx = tid; idx < 352 * 32; idx += 448) {
        const int n = idx >> 5, f = idx & 31, gf = c0 + f;
        unsigned u = 0u;
        if (n < N && gf < F) {
            const int row = b * N + n;
            float v;
            if (gf < DIN) {
                v = x[(size_t)row * DIN + gf];
            } else {
                v = h[(size_t)row * U + (gf - DIN)];
                if (RMUL) v *= ru[(size_t)row * 128 + (gf - DIN)];  // r = ru[:,:64]
            }
            u = pack_hilo(v);
            if (mh == 0 && !(RMUL && gf < DIN))  // x-part identical to gate pass
                zcat[(size_t)row * K3P + gf] = u;
        }
        xls[f * XST + n] = u;
    }
    __syncthreads();

    const int tb = mh * 21 + wave * 3;  // 3 row tiles per wave

    floatx4 acc[3][2];
    #pragma unroll
    for (int i = 0; i < 3; ++i)
        #pragma unroll
        for (int n = 0; n < 2; ++n)
            acc[i][n] = (floatx4){0.f, 0.f, 0.f, 0.f};

    // A-fragment double buffer: prefetch kc+1 while MFMAing kc
    short8 cah[3], cal[3], nah[3], nal[3];
    #pragma unroll
    for (int i = 0; i < 3; ++i) {
        const size_t fo = (size_t)((tb + i) * SSKC) * 64 + lane;
        cah[i] = ssh[fo]; cal[i] = ssl[fo];
    }
    for (int kc = 0; kc < SSKC; ++kc) {
        if (kc + 1 < SSKC) {
            #pragma unroll
            for (int i = 0; i < 3; ++i) {
                const size_t fo = (size_t)((tb + i) * SSKC + kc + 1) * 64 + lane;
                nah[i] = ssh[fo]; nal[i] = ssl[fo];
            }
        }
        // B-fragments: 2x ds_read_b128 per col-tile (conflict-free layout)
        short8 bh[2], bl[2];
        const int koff = kc * 32 + quad * 8;
        #pragma unroll
        for (int n = 0; n < 2; ++n) {
            const uint4 u0 = *(const uint4*)&xls[(n * 16 + l15) * XST + koff];
            const uint4 u1 = *(const uint4*)&xls[(n * 16 + l15) * XST + koff + 4];
            const unsigned uu[8] = {u0.x, u0.y, u0.z, u0.w, u1.x, u1.y, u1.z, u1.w};
            #pragma unroll
            for (int j = 0; j < 8; ++j) {
                bh[n][j] = (short)(uu[j] & 0xffffu);
                bl[n][j] = (short)(uu[j] >> 16);
            }
        }
        #pragma unroll
        for (int i = 0; i < 3; ++i)
            #pragma unroll
            for (int n = 0; n < 2; ++n) {
                acc[i][n] = __builtin_amdgcn_mfma_f32_16x16x32_bf16(cah[i], bh[n], acc[i][n], 0, 0, 0);
                acc[i][n] = __builtin_amdgcn_mfma_f32_16x16x32_bf16(cah[i], bl[n], acc[i][n], 0, 0, 0);
                acc[i][n] = __builtin_amdgcn_mfma_f32_16x16x32_bf16(cal[i], bh[n], acc[i][n], 0, 0, 0);
            }
        if (kc + 1 < SSKC) {
            #pragma unroll
            for (int i = 0; i < 3; ++i) { cah[i] = nah[i]; cal[i] = nal[i]; }
        }
    }

    // epilogue: C/D row=(lane>>4)*4+r, col=lane&15. Rows <325 -> y1 (sect F);
    // rows 336..660 -> y2 (sect 2F); pad rows dropped.
    #pragma unroll
    for (int i = 0; i < 3; ++i) {
        const int t = tb + i;
        #pragma unroll
        for (int n = 0; n < 2; ++n) {
            const int col = c0 + n * 16 + l15;
            if (col >= F) continue;
            #pragma unroll
            for (int r = 0; r < 4; ++r) {
                const int m = t * 16 + quad * 4 + r;
                if (m < N)
                    zcat[(size_t)(b * N + m) * K3P + F + col] = pack_hilo(acc[i][n][r]);
                else if (m >= 336 && m < 336 + N)
                    zcat[(size_t)(b * N + (m - 336)) * K3P + 2 * F + col] = pack_hilo(acc[i][n][r]);
            }
        }
    }
}

// ---------------- dense gate / candidate ----------------
// Gate: ru = sigmoid(zcat @ W + b). Split over col halves (blockIdx.y) for
// 2x blocks -> better latency hiding; halves per-block weight traffic.
__global__ __launch_bounds__(256)
void dense_gate_mfma(const unsigned* __restrict__ zcat, int K3p,
                     const short8* __restrict__ Wh, const short8* __restrict__ Wl,
                     const float* __restrict__ bias, float* __restrict__ ru)
{
    constexpr int NT = 4;                 // col tiles per block (of 8 total)
    const int tid = threadIdx.x, wave = tid >> 6, lane = tid & 63;
    const int quad = lane >> 4, l15 = lane & 15;
    const int row0 = blockIdx.x * 64 + wave * 16;
    const int nb = blockIdx.y * NT;       // global col-tile base

    floatx4 acc[NT];
    #pragma unroll
    for (int n = 0; n < NT; ++n) {
        const float bv = bias[(nb + n) * 16 + l15];
        acc[n] = (floatx4){bv, bv, bv, bv};
    }
    const unsigned* __restrict__ zrow = zcat + (size_t)(row0 + l15) * K3p + quad * 8;
    const int KC = K3p >> 5;
    for (int kc = 0; kc < KC; ++kc) {
        const uint4* p = (const uint4*)(zrow + kc * 32);
        const uint4 u0 = p[0], u1 = p[1];
        const unsigned uu[8] = {u0.x, u0.y, u0.z, u0.w, u1.x, u1.y, u1.z, u1.w};
        short8 ahi, alo;
        #pragma unroll
        for (int j = 0; j < 8; ++j) {
            ahi[j] = (short)(uu[j] & 0xffffu);
            alo[j] = (short)(uu[j] >> 16);
        }
        const short8* __restrict__ wh = Wh + (size_t)(kc * 8 + nb) * 64 + lane;
        const short8* __restrict__ wl = Wl + (size_t)(kc * 8 + nb) * 64 + lane;
        #pragma unroll
        for (int n = 0; n < NT; ++n) {
            const short8 bh = wh[n * 64], bl = wl[n * 64];
            acc[n] = __builtin_amdgcn_mfma_f32_16x16x32_bf16(ahi, bh, acc[n], 0, 0, 0);
            acc[n] = __builtin_amdgcn_mfma_f32_16x16x32_bf16(ahi, bl, acc[n], 0, 0, 0);
            acc[n] = __builtin_amdgcn_mfma_f32_16x16x32_bf16(alo, bh, acc[n], 0, 0, 0);
        }
    }
    #pragma unroll
    for (int n = 0; n < NT; ++n) {
        const int col = (nb + n) * 16 + l15;
        #pragma unroll
        for (int r = 0; r < 4; ++r) {
            const int row = row0 + quad * 4 + r;
            ru[(size_t)row * 128 + col] = 1.f / (1.f + __expf(-acc[n][r]));
        }
    }
}

// Candidate: c = tanh(z@W+b); h = u*h + (1-u)*c. Non-proj variant split over
// col halves (NT=2); proj variant unsplit (needs full 64-col dot).
template<bool PROJ>
__global__ __launch_bounds__(256)
void dense_cand_mfma(const unsigned* __restrict__ zcat, int K3p,
                     const short8* __restrict__ Wh, const short8* __restrict__ Wl,
                     const float* __restrict__ bias, const float* __restrict__ ru,
                     float* __restrict__ h, const float* __restrict__ pW,
                     const float* __restrict__ pb, float* __restrict__ outp,
                     float* __restrict__ dec_in)
{
    constexpr int NT = PROJ ? 4 : 2;
    const int tid = threadIdx.x, wave = tid >> 6, lane = tid & 63;
    const int quad = lane >> 4, l15 = lane & 15;
    const int row0 = blockIdx.x * 64 + wave * 16;
    const int nb = PROJ ? 0 : blockIdx.y * NT;

    floatx4 acc[NT];
    #pragma unroll
    for (int n = 0; n < NT; ++n) {
        const float bv = bias[(nb + n) * 16 + l15];
        acc[n] = (floatx4){bv, bv, bv, bv};
    }
    const unsigned* __restrict__ zrow = zcat + (size_t)(row0 + l15) * K3p + quad * 8;
    const int KC = K3p >> 5;
    for (int kc = 0; kc < KC; ++kc) {
        const uint4* p = (const uint4*)(zrow + kc * 32);
        const uint4 u0 = p[0], u1 = p[1];
        const unsigned uu[8] = {u0.x, u0.y, u0.z, u0.w, u1.x, u1.y, u1.z, u1.w};
        short8 ahi, alo;
        #pragma unroll
        for (int j = 0; j < 8; ++j) {
            ahi[j] = (short)(uu[j] & 0xffffu);
            alo[j] = (short)(uu[j] >> 16);
        }
        const short8* __restrict__ wh = Wh + (size_t)(kc * 4 + nb) * 64 + lane;
        const short8* __restrict__ wl = Wl + (size_t)(kc * 4 + nb) * 64 + lane;
        #pragma unroll
        for (int n = 0; n < NT; ++n) {
            const short8 bh = wh[n * 64], bl = wl[n * 64];
            acc[n] = __builtin_amdgcn_mfma_f32_16x16x32_bf16(ahi, bh, acc[n], 0, 0, 0);
            acc[n] = __builtin_amdgcn_mfma_f32_16x16x32_bf16(ahi, bl, acc[n], 0, 0, 0);
            acc[n] = __builtin_amdgcn_mfma_f32_16x16x32_bf16(alo, bh, acc[n], 0, 0, 0);
        }
    }
    float pr[4] = {0.f, 0.f, 0.f, 0.f};
    #pragma unroll
    for (int n = 0; n < NT; ++n) {
        const int col = (nb + n) * 16 + l15;
        float pw = 0.f;
        if constexpr (PROJ) pw = pW[col];
        #pragma unroll
        for (int r = 0; r < 4; ++r) {
            const int row = row0 + quad * 4 + r;
            const float c  = tanhf(acc[n][r]);
            const float ug = ru[(size_t)row * 128 + 64 + col];  // u = ru[:,64:]
            const float hv = h[(size_t)row * 64 + col];
            const float hn = ug * hv + (1.f - ug) * c;
            h[(size_t)row * 64 + col] = hn;
            if constexpr (PROJ) pr[r] += hn * pw;
        }
    }
    if constexpr (PROJ) {
        #pragma unroll
        for (int r = 0; r < 4; ++r) {
            float v = pr[r];
            v += __shfl_xor(v, 1); v += __shfl_xor(v, 2);
            v += __shfl_xor(v, 4); v += __shfl_xor(v, 8);
            if (l15 == 0) {
                const int row = row0 + quad * 4 + r;
                const float o = v + pb[0];
                outp[row]   = o;
                dec_in[row] = o;
            }
        }
    }
}

// ---------------- host launcher ----------------

extern "C" void kernel_launch(void* const* d_in, const int* in_sizes, int n_in,
                              void* d_out, int out_size, void* d_ws, size_t ws_size,
                              hipStream_t stream)
{
    const float* inputs = (const float*)d_in[0];
    const float* S      = (const float*)d_in[1];
    const float* Wt[4][4];
    for (int l = 0; l < 4; ++l)
        for (int j = 0; j < 4; ++j)
            Wt[l][j] = (const float*)d_in[2 + l * 4 + j];
    const float* pW = (const float*)d_in[18];
    const float* pb = (const float*)d_in[19];
    float* out = (float*)d_out;

    // workspace layout
    float*    ws     = (float*)d_ws;
    float*    h0     = ws;                        // BN*64
    float*    h1     = h0 + (size_t)BN * U;       // BN*64
    float*    dec_in = h1 + (size_t)BN * U;       // BN
    float*    ru     = dec_in + BN;               // BN*128
    unsigned* zcat   = (unsigned*)(ru + (size_t)BN * 128);  // BN*384 (shared 224/384)
    float*    S2     = (float*)(zcat + (size_t)BN * 384);   // N*N
    char*     pp     = (char*)(S2 + (size_t)N * N);
    pp = (char*)(((uintptr_t)pp + 15) & ~(uintptr_t)15);

    short* ssh = (short*)pp;                      // 42*11*64*8 shorts
    short* ssl = ssh + (size_t)SSTIL * SSKC * 64 * 8;
    char*  wpbase = (char*)(ssl + (size_t)SSTIL * SSKC * 64 * 8);

    const int Fs[4]   = {66, 128, 65, 128};
    const int K3ps[4] = {224, 384, 224, 384};
    short *Wgh[4], *Wgl[4], *Wch[4], *Wcl[4];
    size_t off = 0;
    for (int l = 0; l < 4; ++l) {
        const size_t ge = (size_t)K3ps[l] * 128, ce = (size_t)K3ps[l] * 64;
        Wgh[l] = (short*)(wpbase + off); off += ge * 2;
        Wgl[l] = (short*)(wpbase + off); off += ge * 2;
        Wch[l] = (short*)(wpbase + off); off += ce * 2;
        Wcl[l] = (short*)(wpbase + off); off += ce * 2;
    }

    // zero state + zcat (keep pad strips at benign values on first use)
    const long zn = (long)BN * (U + U + 128) + BN + (long)BN * 384;
    zero_kernel<<<2048, 256, 0, stream>>>((unsigned*)h0, zn);

    s2_build<<<N, 256, 0, stream>>>(S, S2);
    prepack_ss<<<dim3(SSTIL, SSKC), 64, 0, stream>>>(S, S2, ssh, ssl);
    for (int l = 0; l < 4; ++l) {
        prepack_w<<<dim3(K3ps[l] / 32, 8), 64, 0, stream>>>(Wt[l][0], Wgh[l], Wgl[l],
                                                            Fs[l], 128, 8);
        prepack_w<<<dim3(K3ps[l] / 32, 4), 64, 0, stream>>>(Wt[l][2], Wch[l], Wcl[l],
                                                            Fs[l], 64, 4);
    }

    const short8* SSH = (const short8*)ssh;
    const short8* SSL = (const short8*)ssl;

    // -------- encoder --------
    for (int t = 0; t < T; ++t) {
        const float* x = inputs + (size_t)t * BN * 2;
        // layer 0: DIN=2, F=66, K3P=224, 3 chunks x 2 M-halves
        diffuse_mfma<2, 66, 224, false><<<dim3(3, B, 2), 448, 0, stream>>>(SSH, SSL, x, h0, ru, zcat);
        dense_gate_mfma<<<dim3(BN / 64, 2), 256, 0, stream>>>(zcat, 224, (short8*)Wgh[0], (short8*)Wgl[0], Wt[0][1], ru);
        diffuse_mfma<2, 66, 224, true><<<dim3(3, B, 2), 448, 0, stream>>>(SSH, SSL, x, h0, ru, zcat);
        dense_cand_mfma<false><<<dim3(BN / 64, 2), 256, 0, stream>>>(zcat, 224, (short8*)Wch[0], (short8*)Wcl[0],
                                                                     Wt[0][3], ru, h0, nullptr, nullptr, nullptr, nullptr);
        // layer 1: DIN=64, F=128, K3P=384, 4 chunks x 2 M-halves
        diffuse_mfma<64, 128, 384, false><<<dim3(4, B, 2), 448, 0, stream>>>(SSH, SSL, h0, h1, ru, zcat);
        dense_gate_mfma<<<dim3(BN / 64, 2), 256, 0, stream>>>(zcat, 384, (short8*)Wgh[1], (short8*)Wgl[1], Wt[1][1], ru);
        diffuse_mfma<64, 128, 384, true><<<dim3(4, B, 2), 448, 0, stream>>>(SSH, SSL, h0, h1, ru, zcat);
        dense_cand_mfma<false><<<dim3(BN / 64, 2), 256, 0, stream>>>(zcat, 384, (short8*)Wch[1], (short8*)Wcl[1],
                                                                     Wt[1][3], ru, h1, nullptr, nullptr, nullptr, nullptr);
    }
    // -------- decoder --------
    for (int hz = 0; hz < HZ; ++hz) {
        // layer 0: DIN=1, F=65, K3P=224
        diffuse_mfma<1, 65, 224, false><<<dim3(3, B, 2), 448, 0, stream>>>(SSH, SSL, dec_in, h0, ru, zcat);
        dense_gate_mfma<<<dim3(BN / 64, 2), 256, 0, stream>>>(zcat, 224, (short8*)Wgh[2], (short8*)Wgl[2], Wt[2][1], ru);
        diffuse_mfma<1, 65, 224, true><<<dim3(3, B, 2), 448, 0, stream>>>(SSH, SSL, dec_in, h0, ru, zcat);
        dense_cand_mfma<false><<<dim3(BN / 64, 2), 256, 0, stream>>>(zcat, 224, (short8*)Wch[2], (short8*)Wcl[2],
                                                                     Wt[2][3], ru, h0, nullptr, nullptr, nullptr, nullptr);
        // layer 1 + fused projection
        diffuse_mfma<64, 128, 384, false><<<dim3(4, B, 2), 448, 0, stream>>>(SSH, SSL, h0, h1, ru, zcat);
        dense_gate_mfma<<<dim3(BN / 64, 2), 256, 0, stream>>>(zcat, 384, (short8*)Wgh[3], (short8*)Wgl[3], Wt[3][1], ru);
        diffuse_mfma<64, 128, 384, true><<<dim3(4, B, 2), 448, 0, stream>>>(SSH, SSL, h0, h1, ru, zcat);
        dense_cand_mfma<true><<<BN / 64, 256, 0, stream>>>(zcat, 384, (short8*)Wch[3], (short8*)Wcl[3],
                                                           Wt[3][3], ru, h1, pW, pb,
                                                           out + (size_t)hz * BN, dec_in);
    }
}